// Round 5
// baseline (190.756 us; speedup 1.0000x reference)
//
#include <hip/hip_runtime.h>
#include <stdint.h>

typedef unsigned short u16;
typedef signed char s8;
typedef int i32x4 __attribute__((ext_vector_type(4)));

#define B_HALF 4096
#define NROWS 8192
#define DCOL 512
#define BM 128
#define BK 128           // i8 bytes per K-tile
#define TT 64            // 8192/128
#define NTILES 2080      // TT*(TT+1)/2
#define KT 4             // DCOL/BK
#define QSCALE 32.0f
#define INV_S2 (1.0f / 1024.0f)

// ---------- kernel A: per-row exact sumsq + i8 quantize + quantized sumsq + colsum ----------
__global__ __launch_bounds__(256) void prep_kernel(const float* __restrict__ src,
    const float* __restrict__ tgt, s8* __restrict__ qp,
    float* __restrict__ sq_exact, float* __restrict__ sqq,
    float* __restrict__ colsum) {
  __shared__ float cs[4][DCOL];
  int lane = threadIdx.x & 63, wid = threadIdx.x >> 6;
  float cpart[8] = {0.f,0.f,0.f,0.f,0.f,0.f,0.f,0.f};
  int row0 = blockIdx.x * 16;
#pragma unroll
  for (int r = 0; r < 4; ++r) {
    int row = row0 + r * 4 + wid;
    const float* x = (row < B_HALF) ? (src + (size_t)row * DCOL)
                                    : (tgt + (size_t)(row - B_HALF) * DCOL);
    float4 v0 = *reinterpret_cast<const float4*>(x + lane * 8);
    float4 v1 = *reinterpret_cast<const float4*>(x + lane * 8 + 4);
    float vals[8] = {v0.x, v0.y, v0.z, v0.w, v1.x, v1.y, v1.z, v1.w};
    union { s8 c[8]; uint2 u; } pu;
    float s = 0.f;
    int iq = 0;
#pragma unroll
    for (int q = 0; q < 8; ++q) {
      float f = vals[q];
      s += f * f;
      cpart[q] += f;
      int k = __float2int_rn(fminf(fmaxf(f * QSCALE, -127.f), 127.f));
      pu.c[q] = (s8)k;
      iq += k * k;
    }
    *reinterpret_cast<uint2*>(qp + (size_t)row * DCOL + lane * 8) = pu.u;
#pragma unroll
    for (int o = 32; o > 0; o >>= 1) {
      s += __shfl_down(s, o);
      iq += __shfl_down(iq, o);
    }
    if (lane == 0) {
      sq_exact[row] = s;
      sqq[row] = (float)iq * INV_S2;   // exact: iq <= 8.26M < 2^23
    }
  }
#pragma unroll
  for (int q = 0; q < 8; ++q) cs[wid][lane * 8 + q] = cpart[q];
  __syncthreads();
  int c = threadIdx.x;
  atomicAdd(&colsum[c],       cs[0][c]       + cs[1][c]       + cs[2][c]       + cs[3][c]);
  atomicAdd(&colsum[c + 256], cs[0][c + 256] + cs[1][c + 256] + cs[2][c + 256] + cs[3][c + 256]);
}

// ---------- kernel B: triangle-tiled i8 MFMA Gram, dbuf 2-phase, fused bw + finalize ----------
#define GLDS(gptr, lptr) __builtin_amdgcn_global_load_lds( \
    (const __attribute__((address_space(1))) void*)(gptr), \
    (__attribute__((address_space(3))) void*)(lptr), 16, 0, 0)

// stage one 64-row half (8 KB) of a 128x128-byte K-tile: 8 loads/wave
#define STAGE(KT_, BUF_) do { \
    const s8* _g = gp0 + (size_t)(KT_) * BK; \
    s8* _l = tileBase + (BUF_) * (BM * BK) + (w1 * 64) * BK; \
    _Pragma("unroll") \
    for (int s_ = 0; s_ < 8; ++s_) \
      GLDS(_g + (size_t)s_ * 8 * DCOL, _l + s_ * 8 * BK); \
  } while (0)

__global__ __launch_bounds__(256, 2) void mmd_gemm_kernel(
    const s8* __restrict__ qp,
    const float* __restrict__ sqq, const float* __restrict__ sq_exact,
    const float* __restrict__ colsum,
    float* __restrict__ partials, unsigned int* __restrict__ counter,
    float* __restrict__ out) {
  __shared__ __align__(16) s8 qA[2][BM * BK];   // 2 x 16 KB
  __shared__ __align__(16) s8 qB[2][BM * BK];   // 2 x 16 KB
  __shared__ float sqR[BM], sqC[BM];
  __shared__ double redS[4], redC[4];
  __shared__ int isLast;

  // bijective XCD swizzle (2080 % 8 == 0), then linear-index -> triangle (I<=J)
  int bid = blockIdx.x;
  int t6 = (bid & 7) * (NTILES / 8) + (bid >> 3);
  int I = 0, rem = t6;
  while (rem >= TT - I) { rem -= TT - I; ++I; }
  int J = I + rem;
  int rowStart = I * BM, colStart = J * BM;

  int tid = threadIdx.x;
  int lane = tid & 63, wid = tid >> 6;
  int wr = wid >> 1, wc = wid & 1, w1 = wid & 1;

  // staging: waves 0,1 -> A halves; waves 2,3 -> B halves.
  // wave covers 8 rows x 128 B per load; lane l: row l>>3, chunk (l&7)^(l>>3)
  // (global pre-swizzle so linear LDS holds the XOR-swizzled layout)
  int rstart = (wid < 2) ? rowStart : colStart;
  const s8* gp0 = qp + (size_t)(rstart + w1 * 64 + (lane >> 3)) * DCOL
                     + (((lane & 7) ^ (lane >> 3)) << 4);
  s8* tileBase = (wid < 2) ? &qA[0][0] : &qB[0][0];

  // fragment read offsets (bytes): row r = base + m*16 + r15, byte = r*128 + pos'*16,
  // pos' = ((ks<<2)|kg) ^ (r15&7)
  int r15 = lane & 15, kg = lane >> 4;
  int aBase = (wr * 64 + r15) * BK;
  int bBase = (wc * 64 + r15) * BK;
  int co0 = ((kg       ^ (r15 & 7)) << 4);
  int co1 = (((4 | kg) ^ (r15 & 7)) << 4);

  // ---- prologue: stage K-tile 0 into buf 0; overlap sq loads + bandwidth ----
  STAGE(0, 0);
  if (tid < BM) sqR[tid] = sqq[rowStart + tid];
  else          sqC[tid - BM] = sqq[colStart + (tid - BM)];

  // in-block bandwidth from EXACT data: bw = (2n*sum(sq) - 2*||colsum||^2)/(n^2-n)
  double ssq = 0.0;
#pragma unroll
  for (int k2 = 0; k2 < 32; ++k2) ssq += (double)sq_exact[tid + 256 * k2];
  double c0 = (double)colsum[tid], c1 = (double)colsum[tid + 256];
  double scs = c0 * c0 + c1 * c1;
#pragma unroll
  for (int o = 32; o > 0; o >>= 1) {
    ssq += __shfl_down(ssq, o);
    scs += __shfl_down(scs, o);
  }
  if (lane == 0) { redS[wid] = ssq; redC[wid] = scs; }
  __syncthreads();                 // drains prologue staging too (vmcnt 0)
  double S = 0.0, C2 = 0.0;
#pragma unroll
  for (int w = 0; w < 4; ++w) { S += redS[w]; C2 += redC[w]; }
  double nn_ = 8192.0;
  double bwv = (2.0 * nn_ * S - 2.0 * C2) / (nn_ * nn_ - nn_);
  float gf = (float)(-1.0 / (16.0 * bwv));

  i32x4 acc[4][4];
#pragma unroll
  for (int m = 0; m < 4; ++m)
#pragma unroll
    for (int n = 0; n < 4; ++n) acc[m][n] = (i32x4){0, 0, 0, 0};

  // ---- main loop: 4 K-tiles, proven 2-phase (stage-next -> read -> MFMA -> sync) ----
#pragma unroll
  for (int kt = 0; kt < KT; ++kt) {
    const int buf = kt & 1;
    if (kt + 1 < KT) STAGE(kt + 1, buf ^ 1);

    i32x4 a[4][2], b[4][2];
#pragma unroll
    for (int m = 0; m < 4; ++m) {
      a[m][0] = *reinterpret_cast<const i32x4*>(&qA[buf][aBase + m * 2048 + co0]);
      a[m][1] = *reinterpret_cast<const i32x4*>(&qA[buf][aBase + m * 2048 + co1]);
    }
#pragma unroll
    for (int n = 0; n < 4; ++n) {
      b[n][0] = *reinterpret_cast<const i32x4*>(&qB[buf][bBase + n * 2048 + co0]);
      b[n][1] = *reinterpret_cast<const i32x4*>(&qB[buf][bBase + n * 2048 + co1]);
    }
#pragma unroll
    for (int m = 0; m < 4; ++m)
#pragma unroll
      for (int n = 0; n < 4; ++n) {
        acc[m][n] = __builtin_amdgcn_mfma_i32_16x16x64_i8(a[m][0], b[n][0], acc[m][n], 0, 0, 0);
        acc[m][n] = __builtin_amdgcn_mfma_i32_16x16x64_i8(a[m][1], b[n][1], acc[m][n], 0, 0, 0);
      }
    __syncthreads();
  }

  // ---- fused epilogue: exact-int dot -> l2 -> u + u^2 + u^4 + u^8 + u^16 ----
  float partial = 0.f;
  int rbase = (lane >> 4) * 4;
#pragma unroll
  for (int m = 0; m < 4; ++m) {
    float sr[4];
#pragma unroll
    for (int e = 0; e < 4; ++e) sr[e] = sqR[wr * 64 + m * 16 + rbase + e];
#pragma unroll
    for (int n = 0; n < 4; ++n) {
      float sc = sqC[wc * 64 + n * 16 + r15];
#pragma unroll
      for (int e = 0; e < 4; ++e) {
        float d = (float)acc[m][n][e] * INV_S2;   // exact (|dot| <= 8.26M < 2^23)
        float l2v = sr[e] + sc - 2.f * d;
        float u = __expf(gf * l2v);
        float u2 = u * u, u4 = u2 * u2, u8 = u4 * u4, u16v = u8 * u8;
        partial += u + u2 + u4 + u8 + u16v;
      }
    }
  }
  float wsign = ((I == J) ? 1.f : 2.f) *
                (((rowStart < B_HALF) == (colStart < B_HALF)) ? 1.f : -1.f);
  partial *= wsign;
#pragma unroll
  for (int o = 32; o > 0; o >>= 1) partial += __shfl_down(partial, o);
  if (lane == 0) partials[bid * 4 + wid] = partial;

  // ---- fused finalize: last block reduces all partials deterministically ----
  __threadfence();
  __syncthreads();
  if (tid == 0) isLast = (atomicAdd(counter, 1u) == NTILES - 1);
  __syncthreads();
  if (isLast) {
    __threadfence();
    double s = 0.0;
    for (int i = tid; i < NTILES * 4; i += 256) s += (double)partials[i];
#pragma unroll
    for (int o = 32; o > 0; o >>= 1) s += __shfl_down(s, o);
    if (lane == 0) redS[wid] = s;
    __syncthreads();
    if (tid == 0) {
      double tot = 0.0;
#pragma unroll
      for (int w = 0; w < 4; ++w) tot += redS[w];
      out[0] = (float)(tot / (4096.0 * 4096.0));
    }
  }
}

extern "C" void kernel_launch(void* const* d_in, const int* in_sizes, int n_in,
                              void* d_out, int out_size, void* d_ws, size_t ws_size,
                              hipStream_t stream) {
  const float* src = (const float*)d_in[0];
  const float* tgt = (const float*)d_in[1];
  char* ws = (char*)d_ws;

  float*        colsum   = (float*)(ws + 0);        // 512 f32 (memset to 0)
  unsigned int* counter  = (unsigned int*)(ws + 2048);
  float*        sq_exact = (float*)(ws + 4096);     // 8192 f32
  float*        sqq      = (float*)(ws + 36864);    // 8192 f32
  float*        partials = (float*)(ws + 69632);    // 2080*4 f32
  s8*           qp       = (s8*)(ws + 131072);      // 8192*512 i8 = 4.19 MB

  hipMemsetAsync(ws, 0, 4096, stream);              // zero colsum + counter

  prep_kernel<<<NROWS / 16, 256, 0, stream>>>(src, tgt, qp, sq_exact, sqq, colsum);
  mmd_gemm_kernel<<<NTILES, 256, 0, stream>>>(qp, sqq, sq_exact, colsum,
                                              partials, counter, (float*)d_out);
}

// Round 6
// 76.858 us; speedup vs baseline: 2.4819x; 2.4819x over previous
//
#include <hip/hip_runtime.h>
#include <stdint.h>

typedef signed char s8;
typedef int i32x4 __attribute__((ext_vector_type(4)));

#define B_HALF 4096
#define NROWS 8192
#define DCOL 512
#define BM 128
#define BK 128           // i8 bytes per K-tile
#define TT 64            // 8192/128
#define NTILES 2080      // TT*(TT+1)/2
#define KT 4             // DCOL/BK
#define QSCALE 32.0f
#define INV_S2 (1.0f / 1024.0f)
#define PREP_BLOCKS (NROWS / 16)   // 512

// ---------- kernel A: quantize + sqq + colsum + global sumsq + last-block bandwidth ----------
__global__ __launch_bounds__(256) void prep_kernel(const float* __restrict__ src,
    const float* __restrict__ tgt, s8* __restrict__ qp,
    float* __restrict__ sqq, float* __restrict__ colsum,
    double* __restrict__ sumsq_acc, unsigned int* __restrict__ counter,
    float* __restrict__ gf_out) {
  __shared__ float cs[4][DCOL];
  __shared__ double redd[4];
  __shared__ int lastFlag;
  int tid = threadIdx.x;
  int lane = tid & 63, wid = tid >> 6;
  float cpart[8] = {0.f,0.f,0.f,0.f,0.f,0.f,0.f,0.f};
  float myssq = 0.f;                 // thread-local exact sum of squares
  int row0 = blockIdx.x * 16;
#pragma unroll
  for (int r = 0; r < 4; ++r) {
    int row = row0 + r * 4 + wid;
    const float* x = (row < B_HALF) ? (src + (size_t)row * DCOL)
                                    : (tgt + (size_t)(row - B_HALF) * DCOL);
    float4 v0 = *reinterpret_cast<const float4*>(x + lane * 8);
    float4 v1 = *reinterpret_cast<const float4*>(x + lane * 8 + 4);
    float vals[8] = {v0.x, v0.y, v0.z, v0.w, v1.x, v1.y, v1.z, v1.w};
    union { s8 c[8]; uint2 u; } pu;
    int iq = 0;
#pragma unroll
    for (int q = 0; q < 8; ++q) {
      float f = vals[q];
      myssq += f * f;
      cpart[q] += f;
      int k = __float2int_rn(fminf(fmaxf(f * QSCALE, -127.f), 127.f));
      pu.c[q] = (s8)k;
      iq += k * k;
    }
    *reinterpret_cast<uint2*>(qp + (size_t)row * DCOL + lane * 8) = pu.u;
#pragma unroll
    for (int o = 32; o > 0; o >>= 1) iq += __shfl_down(iq, o);
    if (lane == 0) sqq[row] = (float)iq * INV_S2;   // exact: iq < 2^23
  }
  // block-level exact sumsq -> one device atomic
  double dssq = (double)myssq;
#pragma unroll
  for (int o = 32; o > 0; o >>= 1) dssq += __shfl_down(dssq, o);
  if (lane == 0) redd[wid] = dssq;
  // column sums via LDS then low-contention atomics
#pragma unroll
  for (int q = 0; q < 8; ++q) cs[wid][lane * 8 + q] = cpart[q];
  __syncthreads();
  int c = tid;
  atomicAdd(&colsum[c],       cs[0][c]       + cs[1][c]       + cs[2][c]       + cs[3][c]);
  atomicAdd(&colsum[c + 256], cs[0][c + 256] + cs[1][c + 256] + cs[2][c + 256] + cs[3][c + 256]);
  if (tid == 0)
    atomicAdd(sumsq_acc, redd[0] + redd[1] + redd[2] + redd[3]);

  // ---- last block computes bandwidth (atomics-only cross-block reads) ----
  asm volatile("s_waitcnt vmcnt(0)" ::: "memory");   // this wave's atomics complete
  __syncthreads();
  if (tid == 0) lastFlag = (atomicAdd(counter, 1u) == PREP_BLOCKS - 1);
  __syncthreads();
  if (lastFlag) {
    float c0 = atomicAdd(&colsum[tid], 0.f);         // atomic-load: coherent at home L2
    float c1 = atomicAdd(&colsum[tid + 256], 0.f);
    double scs = (double)c0 * c0 + (double)c1 * c1;
#pragma unroll
    for (int o = 32; o > 0; o >>= 1) scs += __shfl_down(scs, o);
    if (lane == 0) redd[wid] = scs;
    __syncthreads();
    if (tid == 0) {
      double C2 = redd[0] + redd[1] + redd[2] + redd[3];
      double S = atomicAdd(sumsq_acc, 0.0);          // atomic-load
      double n = (double)NROWS;
      double bwv = (2.0 * n * S - 2.0 * C2) / (n * n - n);
      gf_out[0] = (float)(-1.0 / (16.0 * bwv));      // plain store; next kernel reads
    }
  }
}

// ---------- kernel B: triangle-tiled i8 MFMA Gram — exact round-3 shell ----------
#define GLDS(gptr, lptr) __builtin_amdgcn_global_load_lds( \
    (const __attribute__((address_space(1))) void*)(gptr), \
    (__attribute__((address_space(3))) void*)(lptr), 16, 0, 0)

// stage one 64-row half (8 KB) of a 128x128-byte K-tile: 8 loads/wave
#define STAGE(KT_, BUF_) do { \
    const s8* _g = gp0 + (size_t)(KT_) * BK; \
    s8* _l = tileBase + (BUF_) * (BM * BK) + (w1 * 64) * BK; \
    _Pragma("unroll") \
    for (int s_ = 0; s_ < 8; ++s_) \
      GLDS(_g + (size_t)s_ * 8 * DCOL, _l + s_ * 8 * BK); \
  } while (0)

__global__ __launch_bounds__(256, 2) void mmd_gemm_kernel(
    const s8* __restrict__ qp, const float* __restrict__ sqq,
    const float* __restrict__ gf_ptr, float* __restrict__ partials) {
  __shared__ __align__(16) s8 qA[2][BM * BK];   // 2 x 16 KB
  __shared__ __align__(16) s8 qB[2][BM * BK];   // 2 x 16 KB
  __shared__ float sqR[BM], sqC[BM];

  // bijective XCD swizzle (2080 % 8 == 0), then linear-index -> triangle (I<=J)
  int bid = blockIdx.x;
  int t6 = (bid & 7) * (NTILES / 8) + (bid >> 3);
  int I = 0, rem = t6;
  while (rem >= TT - I) { rem -= TT - I; ++I; }
  int J = I + rem;
  int rowStart = I * BM, colStart = J * BM;

  int tid = threadIdx.x;
  int lane = tid & 63, wid = tid >> 6;
  int wr = wid >> 1, wc = wid & 1, w1 = wid & 1;

  // staging: waves 0,1 -> A halves; waves 2,3 -> B halves.
  // lane l: row l>>3 (of 8), chunk (l&7)^(l>>3) pre-swizzled so linear LDS
  // holds the XOR layout (0 bank conflicts measured, rounds 1-5)
  int rstart = (wid < 2) ? rowStart : colStart;
  const s8* gp0 = qp + (size_t)(rstart + w1 * 64 + (lane >> 3)) * DCOL
                     + (((lane & 7) ^ (lane >> 3)) << 4);
  s8* tileBase = (wid < 2) ? &qA[0][0] : &qB[0][0];

  // fragment read offsets (bytes): LDS pos = chunk ^ (row&7)
  int r15 = lane & 15, kg = lane >> 4;
  int aBase = (wr * 64 + r15) * BK;
  int bBase = (wc * 64 + r15) * BK;
  int co0 = ((kg       ^ (r15 & 7)) << 4);
  int co1 = (((4 | kg) ^ (r15 & 7)) << 4);

  // ---- prologue: stage K-tile 0; sq + gf loads overlap staging latency ----
  STAGE(0, 0);
  if (tid < BM) sqR[tid] = sqq[rowStart + tid];
  else          sqC[tid - BM] = sqq[colStart + (tid - BM)];
  float gf = gf_ptr[0];
  __syncthreads();

  i32x4 acc[4][4];
#pragma unroll
  for (int m = 0; m < 4; ++m)
#pragma unroll
    for (int n = 0; n < 4; ++n) acc[m][n] = (i32x4){0, 0, 0, 0};

  // ---- main loop: proven 2-phase (stage-next -> read -> MFMA -> sync) ----
#pragma unroll
  for (int kt = 0; kt < KT; ++kt) {
    const int buf = kt & 1;
    if (kt + 1 < KT) STAGE(kt + 1, buf ^ 1);

    i32x4 a[4][2], b[4][2];
#pragma unroll
    for (int m = 0; m < 4; ++m) {
      a[m][0] = *reinterpret_cast<const i32x4*>(&qA[buf][aBase + m * 2048 + co0]);
      a[m][1] = *reinterpret_cast<const i32x4*>(&qA[buf][aBase + m * 2048 + co1]);
    }
#pragma unroll
    for (int n = 0; n < 4; ++n) {
      b[n][0] = *reinterpret_cast<const i32x4*>(&qB[buf][bBase + n * 2048 + co0]);
      b[n][1] = *reinterpret_cast<const i32x4*>(&qB[buf][bBase + n * 2048 + co1]);
    }
#pragma unroll
    for (int m = 0; m < 4; ++m)
#pragma unroll
      for (int n = 0; n < 4; ++n) {
        acc[m][n] = __builtin_amdgcn_mfma_i32_16x16x64_i8(a[m][0], b[n][0], acc[m][n], 0, 0, 0);
        acc[m][n] = __builtin_amdgcn_mfma_i32_16x16x64_i8(a[m][1], b[n][1], acc[m][n], 0, 0, 0);
      }
    __syncthreads();
  }

  // ---- fused epilogue: exact-int dot -> l2 -> u + u^2 + u^4 + u^8 + u^16 ----
  float partial = 0.f;
  int rbase = (lane >> 4) * 4;
#pragma unroll
  for (int m = 0; m < 4; ++m) {
    float sr[4];
#pragma unroll
    for (int e = 0; e < 4; ++e) sr[e] = sqR[wr * 64 + m * 16 + rbase + e];
#pragma unroll
    for (int n = 0; n < 4; ++n) {
      float sc = sqC[wc * 64 + n * 16 + r15];
#pragma unroll
      for (int e = 0; e < 4; ++e) {
        float d = (float)acc[m][n][e] * INV_S2;   // exact (|dot| < 2^23)
        float l2v = sr[e] + sc - 2.f * d;
        float u = __expf(gf * l2v);
        float u2 = u * u, u4 = u2 * u2, u8 = u4 * u4, u16v = u8 * u8;
        partial += u + u2 + u4 + u8 + u16v;
      }
    }
  }
  float wsign = ((I == J) ? 1.f : 2.f) *
                (((rowStart < B_HALF) == (colStart < B_HALF)) ? 1.f : -1.f);
  partial *= wsign;
#pragma unroll
  for (int o = 32; o > 0; o >>= 1) partial += __shfl_down(partial, o);
  if (lane == 0) partials[bid * 4 + wid] = partial;   // plain store; no fence/atomic
}

// ---------- kernel C: deterministic finalize (separate launch = coherent reads) ----------
__global__ void finalize_kernel(const float* __restrict__ partials,
                                float* __restrict__ out) {
  __shared__ double red[256];
  int tid = threadIdx.x;
  double s = 0.0;
  for (int i = tid; i < NTILES * 4; i += 256) s += (double)partials[i];
  red[tid] = s;
  __syncthreads();
  for (int o = 128; o > 0; o >>= 1) {
    if (tid < o) red[tid] += red[tid + o];
    __syncthreads();
  }
  if (tid == 0) out[0] = (float)(red[0] / (4096.0 * 4096.0));
}

extern "C" void kernel_launch(void* const* d_in, const int* in_sizes, int n_in,
                              void* d_out, int out_size, void* d_ws, size_t ws_size,
                              hipStream_t stream) {
  const float* src = (const float*)d_in[0];
  const float* tgt = (const float*)d_in[1];
  char* ws = (char*)d_ws;

  float*        colsum    = (float*)(ws + 0);        // 512 f32 (memset to 0)
  unsigned int* counter   = (unsigned int*)(ws + 2048);
  double*       sumsq_acc = (double*)(ws + 2056);
  float*        gfp       = (float*)(ws + 2064);
  float*        sqq       = (float*)(ws + 4096);     // 8192 f32
  float*        partials  = (float*)(ws + 36864);    // 2080*4 f32
  s8*           qp        = (s8*)(ws + 131072);      // 8192*512 i8 = 4.19 MB

  hipMemsetAsync(ws, 0, 4096, stream);               // zero colsum+counter+sumsq

  prep_kernel<<<PREP_BLOCKS, 256, 0, stream>>>(src, tgt, qp, sqq, colsum,
                                               sumsq_acc, counter, gfp);
  mmd_gemm_kernel<<<NTILES, 256, 0, stream>>>(qp, sqq, gfp, partials);
  finalize_kernel<<<1, 256, 0, stream>>>(partials, (float*)d_out);
}

// Round 7
// 75.714 us; speedup vs baseline: 2.5194x; 1.0151x over previous
//
#include <hip/hip_runtime.h>
#include <stdint.h>

typedef signed char s8;
typedef int i32x4 __attribute__((ext_vector_type(4)));

#define B_HALF 4096
#define NROWS 8192
#define DCOL 512
#define BM 128
#define BK 128           // i8 bytes per K-tile
#define TT 64            // 8192/128
#define NTILES 2080      // TT*(TT+1)/2
#define KT 4             // DCOL/BK
#define QSCALE 32.0f
#define INV_S2 (1.0f / 1024.0f)
#define PREP_BLOCKS (NROWS / 16)   // 512

// ---------- kernel Z: zero the 4 KB accumulator region (rocclr 4KB fill = 44 us!) ----------
__global__ void zero_kernel(uint4* __restrict__ p) {
  p[threadIdx.x] = (uint4){0u, 0u, 0u, 0u};   // 256 * 16 B = 4096 B
}

// ---------- kernel A: quantize + sqq + colsum + global sumsq + last-block bandwidth ----------
__global__ __launch_bounds__(256) void prep_kernel(const float* __restrict__ src,
    const float* __restrict__ tgt, s8* __restrict__ qp,
    float* __restrict__ sqq, float* __restrict__ colsum,
    double* __restrict__ sumsq_acc, unsigned int* __restrict__ counter,
    float* __restrict__ gf_out) {
  __shared__ float cs[4][DCOL];
  __shared__ double redd[4];
  __shared__ int lastFlag;
  int tid = threadIdx.x;
  int lane = tid & 63, wid = tid >> 6;
  float cpart[8] = {0.f,0.f,0.f,0.f,0.f,0.f,0.f,0.f};
  float myssq = 0.f;                 // thread-local exact sum of squares
  int row0 = blockIdx.x * 16;
#pragma unroll
  for (int r = 0; r < 4; ++r) {
    int row = row0 + r * 4 + wid;
    const float* x = (row < B_HALF) ? (src + (size_t)row * DCOL)
                                    : (tgt + (size_t)(row - B_HALF) * DCOL);
    float4 v0 = *reinterpret_cast<const float4*>(x + lane * 8);
    float4 v1 = *reinterpret_cast<const float4*>(x + lane * 8 + 4);
    float vals[8] = {v0.x, v0.y, v0.z, v0.w, v1.x, v1.y, v1.z, v1.w};
    union { s8 c[8]; uint2 u; } pu;
    int iq = 0;
#pragma unroll
    for (int q = 0; q < 8; ++q) {
      float f = vals[q];
      myssq += f * f;
      cpart[q] += f;
      int k = __float2int_rn(fminf(fmaxf(f * QSCALE, -127.f), 127.f));
      pu.c[q] = (s8)k;
      iq += k * k;
    }
    *reinterpret_cast<uint2*>(qp + (size_t)row * DCOL + lane * 8) = pu.u;
#pragma unroll
    for (int o = 32; o > 0; o >>= 1) iq += __shfl_down(iq, o);
    if (lane == 0) sqq[row] = (float)iq * INV_S2;   // exact: iq < 2^23
  }
  // block-level exact sumsq -> one device atomic
  double dssq = (double)myssq;
#pragma unroll
  for (int o = 32; o > 0; o >>= 1) dssq += __shfl_down(dssq, o);
  if (lane == 0) redd[wid] = dssq;
  // column sums via LDS then low-contention atomics
#pragma unroll
  for (int q = 0; q < 8; ++q) cs[wid][lane * 8 + q] = cpart[q];
  __syncthreads();
  int c = tid;
  atomicAdd(&colsum[c],       cs[0][c]       + cs[1][c]       + cs[2][c]       + cs[3][c]);
  atomicAdd(&colsum[c + 256], cs[0][c + 256] + cs[1][c + 256] + cs[2][c + 256] + cs[3][c + 256]);
  if (tid == 0)
    atomicAdd(sumsq_acc, redd[0] + redd[1] + redd[2] + redd[3]);

  // ---- last block computes bandwidth (atomics-only cross-block reads) ----
  asm volatile("s_waitcnt vmcnt(0)" ::: "memory");   // this wave's atomics complete
  __syncthreads();
  if (tid == 0) lastFlag = (atomicAdd(counter, 1u) == PREP_BLOCKS - 1);
  __syncthreads();
  if (lastFlag) {
    float c0 = atomicAdd(&colsum[tid], 0.f);         // atomic-load: coherent at home L2
    float c1 = atomicAdd(&colsum[tid + 256], 0.f);
    double scs = (double)c0 * c0 + (double)c1 * c1;
#pragma unroll
    for (int o = 32; o > 0; o >>= 1) scs += __shfl_down(scs, o);
    if (lane == 0) redd[wid] = scs;
    __syncthreads();
    if (tid == 0) {
      double C2 = redd[0] + redd[1] + redd[2] + redd[3];
      double S = atomicAdd(sumsq_acc, 0.0);          // atomic-load
      double n = (double)NROWS;
      double bwv = (2.0 * n * S - 2.0 * C2) / (n * n - n);
      gf_out[0] = (float)(-1.0 / (16.0 * bwv));      // plain store; next kernel reads
    }
  }
}

// ---------- kernel B: triangle-tiled i8 MFMA Gram — proven 2-phase shell ----------
#define GLDS(gptr, lptr) __builtin_amdgcn_global_load_lds( \
    (const __attribute__((address_space(1))) void*)(gptr), \
    (__attribute__((address_space(3))) void*)(lptr), 16, 0, 0)

// stage one 64-row half (8 KB) of a 128x128-byte K-tile: 8 loads/wave
#define STAGE(KT_, BUF_) do { \
    const s8* _g = gp0 + (size_t)(KT_) * BK; \
    s8* _l = tileBase + (BUF_) * (BM * BK) + (w1 * 64) * BK; \
    _Pragma("unroll") \
    for (int s_ = 0; s_ < 8; ++s_) \
      GLDS(_g + (size_t)s_ * 8 * DCOL, _l + s_ * 8 * BK); \
  } while (0)

__global__ __launch_bounds__(256, 2) void mmd_gemm_kernel(
    const s8* __restrict__ qp, const float* __restrict__ sqq,
    const float* __restrict__ gf_ptr, float* __restrict__ partials) {
  __shared__ __align__(16) s8 qA[2][BM * BK];   // 2 x 16 KB
  __shared__ __align__(16) s8 qB[2][BM * BK];   // 2 x 16 KB
  __shared__ float sqR[BM], sqC[BM];

  // bijective XCD swizzle (2080 % 8 == 0), then linear-index -> triangle (I<=J)
  int bid = blockIdx.x;
  int t6 = (bid & 7) * (NTILES / 8) + (bid >> 3);
  int I = 0, rem = t6;
  while (rem >= TT - I) { rem -= TT - I; ++I; }
  int J = I + rem;
  int rowStart = I * BM, colStart = J * BM;

  int tid = threadIdx.x;
  int lane = tid & 63, wid = tid >> 6;
  int wr = wid >> 1, wc = wid & 1, w1 = wid & 1;

  // staging: waves 0,1 -> A halves; waves 2,3 -> B halves.
  // lane l: row l>>3 (of 8), chunk (l&7)^(l>>3) pre-swizzled so linear LDS
  // holds the XOR layout (0 bank conflicts measured, rounds 1-6)
  int rstart = (wid < 2) ? rowStart : colStart;
  const s8* gp0 = qp + (size_t)(rstart + w1 * 64 + (lane >> 3)) * DCOL
                     + (((lane & 7) ^ (lane >> 3)) << 4);
  s8* tileBase = (wid < 2) ? &qA[0][0] : &qB[0][0];

  // fragment read offsets (bytes): LDS pos = chunk ^ (row&7)
  int r15 = lane & 15, kg = lane >> 4;
  int aBase = (wr * 64 + r15) * BK;
  int bBase = (wc * 64 + r15) * BK;
  int co0 = ((kg       ^ (r15 & 7)) << 4);
  int co1 = (((4 | kg) ^ (r15 & 7)) << 4);

  // ---- prologue: stage K-tile 0; sq + gf loads overlap staging latency ----
  STAGE(0, 0);
  if (tid < BM) sqR[tid] = sqq[rowStart + tid];
  else          sqC[tid - BM] = sqq[colStart + (tid - BM)];
  float gf = gf_ptr[0];
  __syncthreads();

  i32x4 acc[4][4];
#pragma unroll
  for (int m = 0; m < 4; ++m)
#pragma unroll
    for (int n = 0; n < 4; ++n) acc[m][n] = (i32x4){0, 0, 0, 0};

  // ---- main loop: proven 2-phase (stage-next -> read -> MFMA -> sync) ----
#pragma unroll
  for (int kt = 0; kt < KT; ++kt) {
    const int buf = kt & 1;
    if (kt + 1 < KT) STAGE(kt + 1, buf ^ 1);

    i32x4 a[4][2], b[4][2];
#pragma unroll
    for (int m = 0; m < 4; ++m) {
      a[m][0] = *reinterpret_cast<const i32x4*>(&qA[buf][aBase + m * 2048 + co0]);
      a[m][1] = *reinterpret_cast<const i32x4*>(&qA[buf][aBase + m * 2048 + co1]);
    }
#pragma unroll
    for (int n = 0; n < 4; ++n) {
      b[n][0] = *reinterpret_cast<const i32x4*>(&qB[buf][bBase + n * 2048 + co0]);
      b[n][1] = *reinterpret_cast<const i32x4*>(&qB[buf][bBase + n * 2048 + co1]);
    }
#pragma unroll
    for (int m = 0; m < 4; ++m)
#pragma unroll
      for (int n = 0; n < 4; ++n) {
        acc[m][n] = __builtin_amdgcn_mfma_i32_16x16x64_i8(a[m][0], b[n][0], acc[m][n], 0, 0, 0);
        acc[m][n] = __builtin_amdgcn_mfma_i32_16x16x64_i8(a[m][1], b[n][1], acc[m][n], 0, 0, 0);
      }
    __syncthreads();
  }

  // ---- fused epilogue: exact-int dot -> l2 -> u + u^2 + u^4 + u^8 + u^16 ----
  float partial = 0.f;
  int rbase = (lane >> 4) * 4;
#pragma unroll
  for (int m = 0; m < 4; ++m) {
    float sr[4];
#pragma unroll
    for (int e = 0; e < 4; ++e) sr[e] = sqR[wr * 64 + m * 16 + rbase + e];
#pragma unroll
    for (int n = 0; n < 4; ++n) {
      float sc = sqC[wc * 64 + n * 16 + r15];
#pragma unroll
      for (int e = 0; e < 4; ++e) {
        float d = (float)acc[m][n][e] * INV_S2;   // exact (|dot| < 2^23)
        float l2v = sr[e] + sc - 2.f * d;
        float u = __expf(gf * l2v);
        float u2 = u * u, u4 = u2 * u2, u8 = u4 * u4, u16v = u8 * u8;
        partial += u + u2 + u4 + u8 + u16v;
      }
    }
  }
  float wsign = ((I == J) ? 1.f : 2.f) *
                (((rowStart < B_HALF) == (colStart < B_HALF)) ? 1.f : -1.f);
  partial *= wsign;
#pragma unroll
  for (int o = 32; o > 0; o >>= 1) partial += __shfl_down(partial, o);
  if (lane == 0) partials[bid * 4 + wid] = partial;   // plain store; no fence/atomic
}

// ---------- kernel C: deterministic finalize (separate launch = coherent reads) ----------
__global__ void finalize_kernel(const float* __restrict__ partials,
                                float* __restrict__ out) {
  __shared__ double red[256];
  int tid = threadIdx.x;
  double s = 0.0;
  for (int i = tid; i < NTILES * 4; i += 256) s += (double)partials[i];
  red[tid] = s;
  __syncthreads();
  for (int o = 128; o > 0; o >>= 1) {
    if (tid < o) red[tid] += red[tid + o];
    __syncthreads();
  }
  if (tid == 0) out[0] = (float)(red[0] / (4096.0 * 4096.0));
}

extern "C" void kernel_launch(void* const* d_in, const int* in_sizes, int n_in,
                              void* d_out, int out_size, void* d_ws, size_t ws_size,
                              hipStream_t stream) {
  const float* src = (const float*)d_in[0];
  const float* tgt = (const float*)d_in[1];
  char* ws = (char*)d_ws;

  float*        colsum    = (float*)(ws + 0);        // 512 f32 (zeroed by zero_kernel)
  unsigned int* counter   = (unsigned int*)(ws + 2048);
  double*       sumsq_acc = (double*)(ws + 2056);
  float*        gfp       = (float*)(ws + 2064);
  float*        sqq       = (float*)(ws + 4096);     // 8192 f32
  float*        partials  = (float*)(ws + 36864);    // 2080*4 f32
  s8*           qp        = (s8*)(ws + 131072);      // 8192*512 i8 = 4.19 MB

  zero_kernel<<<1, 256, 0, stream>>>((uint4*)ws);    // zero colsum+counter+sumsq (4 KB)

  prep_kernel<<<PREP_BLOCKS, 256, 0, stream>>>(src, tgt, qp, sqq, colsum,
                                               sumsq_acc, counter, gfp);
  mmd_gemm_kernel<<<NTILES, 256, 0, stream>>>(qp, sqq, gfp, partials);
  finalize_kernel<<<1, 256, 0, stream>>>(partials, (float*)d_out);
}